// Round 2
// baseline (2406.502 us; speedup 1.0000x reference)
//
#include <hip/hip_runtime.h>

#define HH 640
#define WW 640
#define CIN 3
#define COUT 64
#define KK 7
#define NS 100000
#define OHh 319
#define OWw 319
#define ROWF (WW * CIN)  // 1920 floats per fm row

// ---- detect int64-vs-int32 layout of update_location ----
__global__ void detect_kernel(const int* __restrict__ loc, int* __restrict__ flag) {
    __shared__ int red[256];
    int acc = 0;
    for (int i = 1 + (int)threadIdx.x * 2; i < 2 * NS; i += 512) acc |= loc[i];
    red[threadIdx.x] = acc;
    __syncthreads();
    for (int s = 128; s > 0; s >>= 1) {
        if ((int)threadIdx.x < s) red[threadIdx.x] |= red[threadIdx.x + s];
        __syncthreads();
    }
    if (threadIdx.x == 0) flag[0] = red[0];
}

__device__ __forceinline__ void load_loc(const int* loc, bool is64, int n, int& row, int& col) {
    if (is64) { row = loc[4 * n]; col = loc[4 * n + 2]; }
    else      { row = loc[2 * n]; col = loc[2 * n + 1]; }
}

// ---- owner map: last-write-wins via max site index ----
__global__ void owner_kernel(const int* __restrict__ loc, const int* __restrict__ flag,
                             int* __restrict__ owner) {
    int n = blockIdx.x * blockDim.x + threadIdx.x;
    if (n >= NS) return;
    bool is64 = (flag[0] == 0);
    int row, col;
    load_loc(loc, is64, n, row, col);
    atomicMax(&owner[row * WW + col], n);
}

// ---- per-site conv + BN + ReLU -> feats[NS][64] ----
// 4 sites per wave (lane = cout). Weights in LDS as float4 rows of 24
// (k = j*3+ci in [0,21), padded to 24 with zeros) -> ds_read_b128 shared
// across the 4 sites. Interior sites load each fm kernel-row as 6x16B.
__global__ __launch_bounds__(256, 3) void feats_kernel(
        const int* __restrict__ loc, const float* __restrict__ fm,
        const float* __restrict__ wgt, const float* __restrict__ gamma,
        const float* __restrict__ beta, const float* __restrict__ mean,
        const float* __restrict__ var, const int* __restrict__ flag,
        const int* __restrict__ owner, float* __restrict__ feats) {
    __shared__ float4 WL4[KK * 6 * COUT];          // 7*6*64*16B = 43008 B
    float* wf = (float*)WL4;
    for (int u = threadIdx.x; u < KK * 24 * COUT; u += 256) {
        int cout = u & 63;
        int k = (u >> 6) % 24;
        int i = u / (64 * 24);
        float v = (k < 21) ? wgt[(i * 21 + k) * COUT + cout] : 0.0f;
        wf[((i * 6 + (k >> 2)) * COUT + cout) * 4 + (k & 3)] = v;
    }
    __syncthreads();

    const int lane = threadIdx.x & 63;
    const int wv = threadIdx.x >> 6;
    const bool is64 = (flag[0] == 0);
    const float inv = gamma[lane] * rsqrtf(var[lane] + 1e-5f);
    const float bias = beta[lane] - mean[lane] * inv;

    for (int bg = blockIdx.x; bg < NS / 16; bg += gridDim.x) {
        const int n0 = bg * 16 + wv * 4;

        int rw[4], cl[4];
        bool alive[4], fastp[4];
        #pragma unroll
        for (int s = 0; s < 4; ++s) {
            int r, c;
            load_loc(loc, is64, n0 + s, r, c);
            rw[s] = r; cl[s] = c;
            alive[s] = (owner[r * WW + c] == n0 + s);
            fastp[s] = (r >= 3 && r <= 636 && c >= 3 && c <= 633);
        }

        // slow path: border sites, guarded scalar loads (wave-uniform branch)
        #pragma unroll
        for (int s = 0; s < 4; ++s) {
            if (alive[s] && !fastp[s]) {
                float acc = 0.0f;
                for (int i = 0; i < KK; ++i) {
                    const int r = rw[s] + i - 3;
                    const bool rok = ((unsigned)r < HH);
                    for (int k = 0; k < 21; ++k) {
                        const int j = k / 3, ci = k - 3 * j;
                        const int c = cl[s] + j - 3;
                        const float v = (rok && (unsigned)c < WW)
                                          ? fm[r * ROWF + c * CIN + ci] : 0.0f;
                        const float w = wf[((i * 6 + (k >> 2)) * COUT + lane) * 4 + (k & 3)];
                        acc = fmaf(v, w, acc);
                    }
                }
                feats[(size_t)(n0 + s) * COUT + lane] = fmaxf(acc * inv + bias, 0.0f);
            }
        }

        // fast path: 4 interior sites share each b128 weight read
        float acc[4] = {0.0f, 0.0f, 0.0f, 0.0f};
        const float* ptr[4];
        bool st[4];
        #pragma unroll
        for (int s = 0; s < 4; ++s) {
            st[s] = alive[s] && fastp[s];
            // dead/border sites: load harmlessly from fm base (keeps A in regs)
            ptr[s] = st[s] ? (fm + (rw[s] - 3) * ROWF + (cl[s] - 3) * CIN) : fm;
        }
        for (int i = 0; i < KK; ++i) {
            float A[4][24];
            #pragma unroll
            for (int s = 0; s < 4; ++s) {
                const float* p = ptr[s] + i * ROWF;
                #pragma unroll
                for (int q = 0; q < 6; ++q)
                    __builtin_memcpy(&A[s][q * 4], p + q * 4, 16);  // 4B-aligned 16B load
            }
            #pragma unroll
            for (int k4 = 0; k4 < 6; ++k4) {
                const float4 w = WL4[(i * 6 + k4) * COUT + lane];
                #pragma unroll
                for (int s = 0; s < 4; ++s) {
                    acc[s] = fmaf(A[s][k4 * 4 + 0], w.x, acc[s]);
                    acc[s] = fmaf(A[s][k4 * 4 + 1], w.y, acc[s]);
                    acc[s] = fmaf(A[s][k4 * 4 + 2], w.z, acc[s]);
                    acc[s] = fmaf(A[s][k4 * 4 + 3], w.w, acc[s]);
                }
            }
        }
        #pragma unroll
        for (int s = 0; s < 4; ++s)
            if (st[s])
                feats[(size_t)(n0 + s) * COUT + lane] = fmaxf(acc[s] * inv + bias, 0.0f);
    }
}

// ---- 3x3 stride-2 max pool from owner map + feats; 4 pixels per wave ----
__global__ __launch_bounds__(256) void pool_kernel(
        const int* __restrict__ owner, const float* __restrict__ feats,
        float* __restrict__ out) {
    const int lane = threadIdx.x & 63;
    const int TPR = (OWw + 3) / 4;  // 80 tasks per output row
    const int task = blockIdx.x * 4 + (threadIdx.x >> 6);
    if (task >= OHh * TPR) return;
    const int oh = task / TPR, ow0 = (task % TPR) * 4;
    const int r0 = oh * 2, c0 = ow0 * 2;

    int ov[3][9];
    #pragma unroll
    for (int dy = 0; dy < 3; ++dy) {
        const int* orow = owner + (r0 + dy) * WW;
        #pragma unroll
        for (int dx = 0; dx < 9; ++dx) {
            const int c = c0 + dx;
            ov[dy][dx] = (c < WW) ? orow[c] : -1;
        }
    }
    #pragma unroll
    for (int q = 0; q < 4; ++q) {
        const int ow = ow0 + q;
        if (ow >= OWw) break;
        float m = 0.0f;
        #pragma unroll
        for (int dy = 0; dy < 3; ++dy)
            #pragma unroll
            for (int dx = 0; dx < 3; ++dx) {
                const int o = ov[dy][2 * q + dx];
                if (o >= 0) m = fmaxf(m, feats[(size_t)o * COUT + lane]);
            }
        out[(size_t)(oh * OWw + ow) * COUT + lane] = m;
    }
}

extern "C" void kernel_launch(void* const* d_in, const int* in_sizes, int n_in,
                              void* d_out, int out_size, void* d_ws, size_t ws_size,
                              hipStream_t stream) {
    const int*   loc   = (const int*)d_in[0];
    const float* fm    = (const float*)d_in[1];
    const float* wgt   = (const float*)d_in[2];
    const float* gamma = (const float*)d_in[3];
    const float* beta  = (const float*)d_in[4];
    const float* mean  = (const float*)d_in[5];
    const float* var   = (const float*)d_in[6];
    float* out = (float*)d_out;

    char* ws = (char*)d_ws;
    int* flag    = (int*)ws;                                   // 4 B
    int* owner   = (int*)(ws + 64);                            // 1.6384 MB
    float* feats = (float*)(ws + 64 + (size_t)HH * WW * 4);    // 25.6 MB

    detect_kernel<<<1, 256, 0, stream>>>(loc, flag);
    hipMemsetAsync(owner, 0xFF, (size_t)HH * WW * sizeof(int), stream);  // owner = -1
    owner_kernel<<<(NS + 255) / 256, 256, 0, stream>>>(loc, flag, owner);
    feats_kernel<<<2048, 256, 0, stream>>>(loc, fm, wgt, gamma, beta, mean, var, flag, owner, feats);
    const int tasks = OHh * ((OWw + 3) / 4);
    pool_kernel<<<(tasks + 3) / 4, 256, 0, stream>>>(owner, feats, out);
}

// Round 3
// 283.903 us; speedup vs baseline: 8.4765x; 8.4765x over previous
//
#include <hip/hip_runtime.h>

#define HH 640
#define WW 640
#define CIN 3
#define COUT 64
#define KK 7
#define NS 100000
#define OHh 319
#define OWw 319
#define ROWF (WW * CIN)  // 1920 floats per fm row

// ---- detect int64-vs-int32 layout of update_location (parallel) ----
// OR of odd 32-bit words: zero iff int64 little-endian with values <640.
__global__ void detect_kernel(const int* __restrict__ loc, int* __restrict__ flag) {
    __shared__ int red[256];
    int acc = 0;
    const int start = 1 + 2 * (blockIdx.x * 256 + threadIdx.x);
    const int stride = 2 * gridDim.x * 256;
    for (int i = start; i < 2 * NS; i += stride) acc |= loc[i];
    red[threadIdx.x] = acc;
    __syncthreads();
    for (int s = 128; s > 0; s >>= 1) {
        if ((int)threadIdx.x < s) red[threadIdx.x] |= red[threadIdx.x + s];
        __syncthreads();
    }
    if (threadIdx.x == 0 && red[0]) atomicOr(flag, 1);
}

// ---- owner map: last-write-wins via max site index ----
__global__ void owner_kernel(const int* __restrict__ loc, const int* __restrict__ flag,
                             int* __restrict__ owner) {
    int n = blockIdx.x * blockDim.x + threadIdx.x;
    if (n >= NS) return;
    bool is64 = (flag[0] == 0);
    int row, col;
    if (is64) { row = loc[4 * n]; col = loc[4 * n + 2]; }
    else      { row = loc[2 * n]; col = loc[2 * n + 1]; }
    atomicMax(&owner[row * WW + col], n);
}

// ---- per-site conv + BN + ReLU -> feats[NS][64] ----
// 4 sites/wave, lane = cout. All patch addresses are wave-uniform ->
// readfirstlane forces them onto the SCALAR pipe (s_load into SGPRs),
// leaving VGPRs for accs + one float4 weight (ds_read_b128, shared x4).
__global__ __launch_bounds__(256) void feats_kernel(
        const int* __restrict__ loc, const float* __restrict__ fm,
        const float* __restrict__ wgt, const float* __restrict__ gamma,
        const float* __restrict__ beta, const float* __restrict__ mean,
        const float* __restrict__ var, const int* __restrict__ flag,
        const int* __restrict__ owner, float* __restrict__ feats) {
    __shared__ float4 WL4[KK * 6 * COUT];  // [i][k4][cout], k padded 21->24; 43008 B
    float* wf = (float*)WL4;
    for (int u = threadIdx.x; u < KK * 24 * COUT; u += 256) {
        int cout = u & 63;
        int k = (u >> 6) % 24;
        int i = u / (64 * 24);
        float v = (k < 21) ? wgt[(i * 21 + k) * COUT + cout] : 0.0f;
        wf[((i * 6 + (k >> 2)) * COUT + cout) * 4 + (k & 3)] = v;
    }
    __syncthreads();

    const int lane = threadIdx.x & 63;
    const int wv = threadIdx.x >> 6;
    const bool is64 = (flag[0] == 0);
    const float inv = gamma[lane] * rsqrtf(var[lane] + 1e-5f);
    const float bias = beta[lane] - mean[lane] * inv;

    for (int bg = blockIdx.x; bg < NS / 16; bg += gridDim.x) {
        const int n0 = __builtin_amdgcn_readfirstlane(bg * 16 + wv * 4);

        int rw[4], cl[4];
        bool alive[4], fastp[4];
        #pragma unroll
        for (int s = 0; s < 4; ++s) {
            const int n = n0 + s;
            int r, c;
            if (is64) { r = loc[4 * n]; c = loc[4 * n + 2]; }
            else      { r = loc[2 * n]; c = loc[2 * n + 1]; }
            r = __builtin_amdgcn_readfirstlane(r);
            c = __builtin_amdgcn_readfirstlane(c);
            rw[s] = r; cl[s] = c;
            alive[s] = (owner[r * WW + c] == n);
            fastp[s] = (r >= 3 && r <= 636 && c >= 3 && c <= 633);
        }

        // slow path: border sites (~2.3%), guarded scalar loads (uniform branch)
        #pragma unroll
        for (int s = 0; s < 4; ++s) {
            if (alive[s] && !fastp[s]) {
                float acc = 0.0f;
                for (int i = 0; i < KK; ++i) {
                    const int r = rw[s] + i - 3;
                    const bool rok = ((unsigned)r < HH);
                    for (int k = 0; k < 21; ++k) {
                        const int j = k / 3, ci = k - 3 * j;
                        const int c = cl[s] + j - 3;
                        const float v = (rok && (unsigned)c < WW)
                                          ? fm[r * ROWF + c * CIN + ci] : 0.0f;
                        const float w = wf[((i * 6 + (k >> 2)) * COUT + lane) * 4 + (k & 3)];
                        acc = fmaf(v, w, acc);
                    }
                }
                feats[(size_t)(n0 + s) * COUT + lane] = fmaxf(acc * inv + bias, 0.0f);
            }
        }

        // fast path: 4 interior sites share each b128 weight read; patch on scalar pipe
        bool st[4];
        const float* ptr[4];
        #pragma unroll
        for (int s = 0; s < 4; ++s) {
            st[s] = alive[s] && fastp[s];
            ptr[s] = st[s] ? (fm + (rw[s] - 3) * ROWF + (cl[s] - 3) * CIN) : fm;
        }
        if (st[0] | st[1] | st[2] | st[3]) {
            float acc[4] = {0.0f, 0.0f, 0.0f, 0.0f};
            #pragma unroll 1
            for (int i = 0; i < KK; ++i) {
                #pragma unroll 1
                for (int h = 0; h < 2; ++h) {
                    float a[4][12];
                    #pragma unroll
                    for (int s = 0; s < 4; ++s) {
                        const float* p = ptr[s] + i * ROWF + h * 12;
                        #pragma unroll
                        for (int j = 0; j < 12; ++j) a[s][j] = p[j];  // uniform -> s_load
                    }
                    #pragma unroll
                    for (int k4 = 0; k4 < 3; ++k4) {
                        const float4 w = WL4[(i * 6 + h * 3 + k4) * COUT + lane];
                        #pragma unroll
                        for (int s = 0; s < 4; ++s) {
                            acc[s] = fmaf(a[s][k4 * 4 + 0], w.x, acc[s]);
                            acc[s] = fmaf(a[s][k4 * 4 + 1], w.y, acc[s]);
                            acc[s] = fmaf(a[s][k4 * 4 + 2], w.z, acc[s]);
                            acc[s] = fmaf(a[s][k4 * 4 + 3], w.w, acc[s]);
                        }
                    }
                }
            }
            #pragma unroll
            for (int s = 0; s < 4; ++s)
                if (st[s])
                    feats[(size_t)(n0 + s) * COUT + lane] = fmaxf(acc[s] * inv + bias, 0.0f);
        }
    }
}

// ---- 3x3 stride-2 max pool from owner map + feats; 4 pixels per wave ----
// Owner loads are wave-uniform -> scalar pipe; feats gather coalesced 256B.
__global__ __launch_bounds__(256) void pool_kernel(
        const int* __restrict__ owner, const float* __restrict__ feats,
        float* __restrict__ out) {
    const int lane = threadIdx.x & 63;
    const int TPR = 80;  // ceil(319/4) tasks per output row
    const int task = __builtin_amdgcn_readfirstlane(blockIdx.x * 4 + (threadIdx.x >> 6));
    if (task >= OHh * TPR) return;
    const int oh = task / TPR, ow0 = (task % TPR) * 4;
    const int r0 = oh * 2, c0 = ow0 * 2;

    int ov[3][9];
    #pragma unroll
    for (int dy = 0; dy < 3; ++dy) {
        const int* orow = owner + (r0 + dy) * WW + c0;
        #pragma unroll
        for (int dx = 0; dx < 9; ++dx)
            ov[dy][dx] = (c0 + dx < WW) ? orow[dx] : -1;  // uniform -> s_load
    }
    #pragma unroll
    for (int q = 0; q < 4; ++q) {
        const int ow = ow0 + q;
        if (ow >= OWw) break;
        float m = 0.0f;
        #pragma unroll
        for (int dy = 0; dy < 3; ++dy)
            #pragma unroll
            for (int dx = 0; dx < 3; ++dx) {
                const int o = ov[dy][2 * q + dx];
                if (o >= 0) m = fmaxf(m, feats[(size_t)o * COUT + lane]);
            }
        out[(size_t)(oh * OWw + ow) * COUT + lane] = m;
    }
}

extern "C" void kernel_launch(void* const* d_in, const int* in_sizes, int n_in,
                              void* d_out, int out_size, void* d_ws, size_t ws_size,
                              hipStream_t stream) {
    const int*   loc   = (const int*)d_in[0];
    const float* fm    = (const float*)d_in[1];
    const float* wgt   = (const float*)d_in[2];
    const float* gamma = (const float*)d_in[3];
    const float* beta  = (const float*)d_in[4];
    const float* mean  = (const float*)d_in[5];
    const float* var   = (const float*)d_in[6];
    float* out = (float*)d_out;

    char* ws = (char*)d_ws;
    int* flag    = (int*)ws;                                   // 4 B
    int* owner   = (int*)(ws + 64);                            // 1.6384 MB
    float* feats = (float*)(ws + 64 + (size_t)HH * WW * 4);    // 25.6 MB

    hipMemsetAsync(flag, 0, sizeof(int), stream);
    detect_kernel<<<64, 256, 0, stream>>>(loc, flag);
    hipMemsetAsync(owner, 0xFF, (size_t)HH * WW * sizeof(int), stream);  // owner = -1
    owner_kernel<<<(NS + 255) / 256, 256, 0, stream>>>(loc, flag, owner);
    feats_kernel<<<1024, 256, 0, stream>>>(loc, fm, wgt, gamma, beta, mean, var, flag, owner, feats);
    pool_kernel<<<(OHh * 80) / 4, 256, 0, stream>>>(owner, feats, out);
}

// Round 4
// 189.148 us; speedup vs baseline: 12.7229x; 1.5010x over previous
//
#include <hip/hip_runtime.h>

#define HH 640
#define WW 640
#define CIN 3
#define COUT 64
#define KK 7
#define NS 100000
#define OHh 319
#define OWw 319
#define PW 646                 // padded width/height
#define PROWF (PW * CIN)       // 1938 floats per padded row
#define WROW 1344              // LDS floats per kernel row: 5*256 + 64

// bf16 helpers (RNE)
__device__ __forceinline__ unsigned short f2bf(float x) {
    unsigned u = __float_as_uint(x);
    unsigned r = (u + 0x7FFFu + ((u >> 16) & 1u)) >> 16;
    return (unsigned short)r;
}
__device__ __forceinline__ float bf2f(unsigned short b) {
    return __uint_as_float((unsigned)b << 16);
}

// ---- detect int64-vs-int32 layout of update_location ----
__global__ void detect_kernel(const int* __restrict__ loc, int* __restrict__ flag) {
    __shared__ int red[256];
    int acc = 0;
    const int start = 1 + 2 * (blockIdx.x * 256 + threadIdx.x);
    const int stride = 2 * gridDim.x * 256;
    for (int i = start; i < 2 * NS; i += stride) acc |= loc[i];
    red[threadIdx.x] = acc;
    __syncthreads();
    for (int s = 128; s > 0; s >>= 1) {
        if ((int)threadIdx.x < s) red[threadIdx.x] |= red[threadIdx.x + s];
        __syncthreads();
    }
    if (threadIdx.x == 0 && red[0]) atomicOr(flag, 1);
}

// ---- owner map: last-write-wins via max site index ----
__global__ void owner_kernel(const int* __restrict__ loc, const int* __restrict__ flag,
                             int* __restrict__ owner) {
    int n = blockIdx.x * blockDim.x + threadIdx.x;
    if (n >= NS) return;
    bool is64 = (flag[0] == 0);
    int row, col;
    if (is64) { row = loc[4 * n]; col = loc[4 * n + 2]; }
    else      { row = loc[2 * n]; col = loc[2 * n + 1]; }
    atomicMax(&owner[row * WW + col], n);
}

// ---- zero-padded copy of fm: pfm[646][646][3] ----
__global__ void pad_kernel(const float* __restrict__ fm, float* __restrict__ pfm) {
    const int pix = blockIdx.x * 256 + threadIdx.x;
    if (pix >= PW * PW) return;
    const int r = pix / PW, c = pix % PW;
    float v0 = 0.0f, v1 = 0.0f, v2 = 0.0f;
    if (r >= 3 && r < 643 && c >= 3 && c < 643) {
        const float* s = fm + ((size_t)(r - 3) * WW + (c - 3)) * CIN;
        v0 = s[0]; v1 = s[1]; v2 = s[2];
    }
    float* d = pfm + (size_t)pix * CIN;
    d[0] = v0; d[1] = v1; d[2] = v2;
}

// ---- per-site conv + BN + ReLU -> feats[NS][64] (bf16) ----
// 4 sites/wave, lane = cout. Patch loads: wave-uniform -> scalar pipe (SGPRs).
// Weights in LDS: per row i, 5 float4 groups (k=0..19) + 1 scalar (k=20);
// 37632 B -> 4 blocks/CU. Padded fm removes all border guards.
__global__ __launch_bounds__(256) void feats_kernel(
        const int* __restrict__ loc, const float* __restrict__ pfm,
        const float* __restrict__ wgt, const float* __restrict__ gamma,
        const float* __restrict__ beta, const float* __restrict__ mean,
        const float* __restrict__ var, const int* __restrict__ flag,
        const int* __restrict__ owner, unsigned short* __restrict__ feats) {
    __shared__ float WL[KK * WROW];  // 9408 floats = 37632 B
    for (int u = threadIdx.x; u < KK * 21 * COUT; u += 256) {
        const int cout = u & 63;
        const int k = (u >> 6) % 21;
        const int i = u / (21 * 64);
        const int off = (k < 20) ? (i * WROW + (k >> 2) * 256 + cout * 4 + (k & 3))
                                 : (i * WROW + 1280 + cout);
        WL[off] = wgt[u];  // u == (i*21+k)*64+cout
    }
    __syncthreads();

    const int lane = threadIdx.x & 63;
    const int wv = threadIdx.x >> 6;
    const bool is64 = (flag[0] == 0);
    const float inv = gamma[lane] * rsqrtf(var[lane] + 1e-5f);
    const float bias = beta[lane] - mean[lane] * inv;

    for (int bg = blockIdx.x; bg < NS / 16; bg += gridDim.x) {
        const int n0 = __builtin_amdgcn_readfirstlane(bg * 16 + wv * 4);

        const float* ptr[4];
        bool alive[4];
        #pragma unroll
        for (int s = 0; s < 4; ++s) {
            const int n = n0 + s;
            int r, c;
            if (is64) { r = loc[4 * n]; c = loc[4 * n + 2]; }
            else      { r = loc[2 * n]; c = loc[2 * n + 1]; }
            r = __builtin_amdgcn_readfirstlane(r);
            c = __builtin_amdgcn_readfirstlane(c);
            alive[s] = (owner[r * WW + c] == n);
            ptr[s] = pfm + ((size_t)r * PW + c) * CIN;  // row i at +i*PROWF
        }

        float acc[4] = {0.0f, 0.0f, 0.0f, 0.0f};
        #pragma unroll 1
        for (int i = 0; i < KK; ++i) {
            // chunk A: k = 0..11 (3 float4 weight groups)
            {
                float a[4][12];
                #pragma unroll
                for (int s = 0; s < 4; ++s) {
                    const float* p = ptr[s] + i * PROWF;
                    #pragma unroll
                    for (int j = 0; j < 12; ++j) a[s][j] = p[j];  // uniform -> s_load
                }
                #pragma unroll
                for (int g = 0; g < 3; ++g) {
                    const float4 w = *(const float4*)&WL[i * WROW + g * 256 + lane * 4];
                    #pragma unroll
                    for (int s = 0; s < 4; ++s) {
                        acc[s] = fmaf(a[s][g * 4 + 0], w.x, acc[s]);
                        acc[s] = fmaf(a[s][g * 4 + 1], w.y, acc[s]);
                        acc[s] = fmaf(a[s][g * 4 + 2], w.z, acc[s]);
                        acc[s] = fmaf(a[s][g * 4 + 3], w.w, acc[s]);
                    }
                }
            }
            // chunk B: k = 12..20 (2 float4 groups + scalar k=20)
            {
                float b[4][9];
                #pragma unroll
                for (int s = 0; s < 4; ++s) {
                    const float* p = ptr[s] + i * PROWF + 12;
                    #pragma unroll
                    for (int j = 0; j < 9; ++j) b[s][j] = p[j];
                }
                #pragma unroll
                for (int g = 0; g < 2; ++g) {
                    const float4 w = *(const float4*)&WL[i * WROW + (3 + g) * 256 + lane * 4];
                    #pragma unroll
                    for (int s = 0; s < 4; ++s) {
                        acc[s] = fmaf(b[s][g * 4 + 0], w.x, acc[s]);
                        acc[s] = fmaf(b[s][g * 4 + 1], w.y, acc[s]);
                        acc[s] = fmaf(b[s][g * 4 + 2], w.z, acc[s]);
                        acc[s] = fmaf(b[s][g * 4 + 3], w.w, acc[s]);
                    }
                }
                const float w20 = WL[i * WROW + 1280 + lane];
                #pragma unroll
                for (int s = 0; s < 4; ++s) acc[s] = fmaf(b[s][8], w20, acc[s]);
            }
        }
        #pragma unroll
        for (int s = 0; s < 4; ++s)
            if (alive[s])
                feats[(size_t)(n0 + s) * COUT + lane] =
                    f2bf(fmaxf(acc[s] * inv + bias, 0.0f));
    }
}

// ---- 3x3 stride-2 max pool from owner map + bf16 feats; 4 px per wave ----
__global__ __launch_bounds__(256) void pool_kernel(
        const int* __restrict__ owner, const unsigned short* __restrict__ feats,
        float* __restrict__ out) {
    const int lane = threadIdx.x & 63;
    const int TPR = 80;  // ceil(319/4)
    const int task = __builtin_amdgcn_readfirstlane(blockIdx.x * 4 + (threadIdx.x >> 6));
    if (task >= OHh * TPR) return;
    const int oh = task / TPR, ow0 = (task % TPR) * 4;
    const int r0 = oh * 2, c0 = ow0 * 2;

    int ov[3][9];
    #pragma unroll
    for (int dy = 0; dy < 3; ++dy) {
        const int* orow = owner + (r0 + dy) * WW + c0;
        #pragma unroll
        for (int dx = 0; dx < 9; ++dx)
            ov[dy][dx] = (c0 + dx < WW) ? orow[dx] : -1;  // uniform -> s_load
    }
    #pragma unroll
    for (int q = 0; q < 4; ++q) {
        const int ow = ow0 + q;
        if (ow >= OWw) break;
        float m = 0.0f;
        #pragma unroll
        for (int dy = 0; dy < 3; ++dy)
            #pragma unroll
            for (int dx = 0; dx < 3; ++dx) {
                const int o = ov[dy][2 * q + dx];
                if (o >= 0) m = fmaxf(m, bf2f(feats[(size_t)o * COUT + lane]));
            }
        out[(size_t)(oh * OWw + ow) * COUT + lane] = m;
    }
}

extern "C" void kernel_launch(void* const* d_in, const int* in_sizes, int n_in,
                              void* d_out, int out_size, void* d_ws, size_t ws_size,
                              hipStream_t stream) {
    const int*   loc   = (const int*)d_in[0];
    const float* fm    = (const float*)d_in[1];
    const float* wgt   = (const float*)d_in[2];
    const float* gamma = (const float*)d_in[3];
    const float* beta  = (const float*)d_in[4];
    const float* mean  = (const float*)d_in[5];
    const float* var   = (const float*)d_in[6];
    float* out = (float*)d_out;

    char* ws = (char*)d_ws;
    int* flag = (int*)ws;                                         // 4 B @ 0
    int* owner = (int*)(ws + 64);                                 // 1638400 B
    unsigned short* feats = (unsigned short*)(ws + 64 + 1638400); // 12.8 MB
    float* pfm = (float*)(ws + 64 + 1638400 + (size_t)NS * COUT * 2);  // 5.0 MB
    // total ~19.5 MB

    hipMemsetAsync(flag, 0, sizeof(int), stream);
    detect_kernel<<<64, 256, 0, stream>>>(loc, flag);
    hipMemsetAsync(owner, 0xFF, (size_t)HH * WW * sizeof(int), stream);
    owner_kernel<<<(NS + 255) / 256, 256, 0, stream>>>(loc, flag, owner);
    pad_kernel<<<(PW * PW + 255) / 256, 256, 0, stream>>>(fm, pfm);
    feats_kernel<<<1024, 256, 0, stream>>>(loc, pfm, wgt, gamma, beta, mean, var,
                                           flag, owner, feats);
    pool_kernel<<<(OHh * 80) / 4, 256, 0, stream>>>(owner, feats, out);
}